// Round 10
// baseline (318.199 us; speedup 1.0000x reference)
//
#include <hip/hip_runtime.h>

typedef unsigned short u16;

#define NGRAPH 16
#define SEQ    1024
#define DIM    128
#define NHEAD  2
#define HDIM   64
#define KPOS   20
#define NTOT   (NGRAPH*SEQ)     // 16384
#define QKVD   (3*DIM)          // 384

// ---------- bf16 helpers ----------------------------------------------------
__device__ __forceinline__ float bf2f(u16 u) {
    return __uint_as_float(((unsigned int)u) << 16);
}
__device__ __forceinline__ u16 f2bf(float f) {
    unsigned int u = __float_as_uint(f);
    u += 0x7fffu + ((u >> 16) & 1u);   // RNE
    return (u16)(u >> 16);
}
__device__ __forceinline__ float ld1(const void* p, int fbf, size_t i) {
    return fbf ? bf2f(((const u16*)p)[i]) : ((const float*)p)[i];
}

typedef __attribute__((ext_vector_type(8))) short bf16x8;
typedef __attribute__((ext_vector_type(4))) float f32x4;

// 8 contiguous weights -> bf16x8 fragment (direct 16B load when bf16)
__device__ __forceinline__ bf16x8 ldbf8(const void* W, int fbf, size_t i) {
    float4 r;
    if (fbf) {
        r = *(const float4*)((const u16*)W + i);
    } else {
        const float* q = (const float*)W + i;
        float4 a = *(const float4*)q, b = *(const float4*)(q + 4);
        u16* d = (u16*)&r;
        d[0]=f2bf(a.x); d[1]=f2bf(a.y); d[2]=f2bf(a.z); d[3]=f2bf(a.w);
        d[4]=f2bf(b.x); d[5]=f2bf(b.y); d[6]=f2bf(b.z); d[7]=f2bf(b.w);
    }
    return *(bf16x8*)&r;
}

// ---------- per-wave dtype detection (no kernel, no flag buffer) -----------
// bf16 data: u16s are bf16 of N(0,1)-ish -> exponent in [60,180].
// f32 data: even u16s are mantissa bits -> ~uniform exponent; P(miss)=1e-42.
__device__ __forceinline__ int detect_fbf(const u16* x) {
    int lane = threadIdx.x & 63;
    unsigned ea = (x[2 * lane]       >> 7) & 0xFF;
    unsigned eb = (x[2 * lane + 128] >> 7) & 0xFF;
    int ok = (ea >= 60u && ea <= 180u) && (eb >= 60u && eb <= 180u);
    return (int)(__ballot(ok) == 0xFFFFFFFFFFFFFFFFull);
}

// ---------- K1: fused pe + qkv, 1-wave blocks, zero barriers ---------------
// Block = 64 threads (1 wave) owns 16 rows. pe via K=32 zero-padded MFMA;
// h0 -> d_out slots (residual) + wave-local LDS -> A-frags; qkv = h0 @ in_w^T
// with B-fragments loaded directly from global (L2-hot weights).
__global__ __launch_bounds__(64)
void peqkv_kernel(const void* __restrict__ x, const void* __restrict__ pos,
                  const void* __restrict__ pe_w, const void* __restrict__ pe_b,
                  const void* __restrict__ in_w, const void* __restrict__ in_b,
                  u16* __restrict__ h0out, u16* __restrict__ qkv,
                  int arow0, int qrow0) {
    int fbf = detect_fbf((const u16*)x);
    int rs  = fbf ? 128 : 256;
    __shared__ u16 h0sh[16][136];
    int lane = threadIdx.x;
    int l16 = lane & 15, quad = lane >> 4;
    int n0 = blockIdx.x * 16;

    // pos A-frag (16 rows x 32 k, k>=20 zero)
    bf16x8 pa;
    {
        u16 tmp[8];
        size_t base = (size_t)(arow0 + n0 + l16) * KPOS;
#pragma unroll
        for (int j = 0; j < 8; ++j) {
            int k = quad * 8 + j;
            tmp[j] = (k < KPOS) ? f2bf(ld1(pos, fbf, base + k)) : (u16)0;
        }
        pa = *(bf16x8*)tmp;
    }
    // pe_w B-frags (8 col-subtiles x 32 k, zero-padded)
    f32x4 hacc[8];
#pragma unroll
    for (int s = 0; s < 8; ++s) {
        u16 tmp[8];
        size_t base = (size_t)(s * 16 + l16) * KPOS;
#pragma unroll
        for (int j = 0; j < 8; ++j) {
            int k = quad * 8 + j;
            tmp[j] = (k < KPOS) ? f2bf(ld1(pe_w, fbf, base + k)) : (u16)0;
        }
        bf16x8 pwb = *(bf16x8*)tmp;
        f32x4 z = {};
        hacc[s] = __builtin_amdgcn_mfma_f32_16x16x32_bf16(pa, pwb, z, 0, 0, 0);
    }
    // h0 = x + pe + pe_b -> slots + LDS
#pragma unroll
    for (int s = 0; s < 8; ++s) {
        float pb = ld1(pe_b, fbf, s * 16 + l16);
#pragma unroll
        for (int r = 0; r < 4; ++r) {
            size_t n = (size_t)(arow0 + n0 + quad * 4 + r);
            float h = hacc[s][r] + ld1(x, fbf, n * DIM + s * 16 + l16) + pb;
            u16 hb = f2bf(h);
            h0sh[quad * 4 + r][s * 16 + l16] = hb;
            h0out[n * rs + s * 16 + l16] = hb;
        }
    }
    // A-frags from LDS (wave-local; compiler inserts lgkmcnt)
    bf16x8 af[4];
#pragma unroll
    for (int kk = 0; kk < 4; ++kk)
        af[kk] = *(const bf16x8*)&h0sh[l16][kk * 32 + quad * 8];
    // qkv: 3 chunks of 128 cols, B-frags straight from global
#pragma unroll 1
    for (int c = 0; c < 3; ++c) {
        f32x4 acc[8] = {};
#pragma unroll
        for (int kk = 0; kk < 4; ++kk) {
#pragma unroll
            for (int s = 0; s < 8; ++s) {
                bf16x8 bf = ldbf8(in_w, fbf,
                    (size_t)(c * 128 + s * 16 + l16) * DIM + kk * 32 + quad * 8);
                acc[s] = __builtin_amdgcn_mfma_f32_16x16x32_bf16(af[kk], bf, acc[s], 0, 0, 0);
            }
        }
#pragma unroll
        for (int s = 0; s < 8; ++s) {
            float bb = ld1(in_b, fbf, c * 128 + s * 16 + l16);
#pragma unroll
            for (int r = 0; r < 4; ++r)
                qkv[(size_t)(qrow0 + n0 + quad * 4 + r) * QKVD
                    + c * 128 + s * 16 + l16] = f2bf(acc[s][r] + bb);
        }
    }
}

// ---------- K2: flash attention (R7 kernel verbatim — measured 47 us) ------
__global__ __launch_bounds__(256)
void attn_kernel(const u16* __restrict__ qkv, u16* __restrict__ ctx) {
    __shared__ u16 Qsh[64][72];
    __shared__ u16 Ksh[64][72];
    __shared__ u16 VshT[64][72];
    __shared__ u16 Psh[64][72];
    int t    = threadIdx.x;
    int w    = t >> 6;
    int lane = t & 63;
    int l16  = lane & 15;
    int quad = lane >> 4;
    int L = blockIdx.x;
    int ngh = gridDim.x >> 4;
    int qt, gh;
    if (ngh >= 8) {           // XCD swizzle: gh%8 == L%8
        int g8 = L & 7; int rest = L >> 3;
        qt = rest & 15; gh = (rest >> 4) * 8 + g8;
    } else {
        qt = L & 15; gh = L >> 4;
    }
    int b = gh >> 1, h = gh & 1;

#pragma unroll
    for (int i = 0; i < 2; ++i) {
        int idx = t + i * 256;
        int r = idx >> 3, d8 = (idx & 7) * 8;
        size_t n = (size_t)b * SEQ + qt * 64 + r;
        *(float4*)&Qsh[r][d8] = *(const float4*)&qkv[n * QKVD + h * HDIM + d8];
    }
    int kr = t >> 3, kd8 = (t & 7) * 8;
    int vr = t & 63, vdb = (t >> 6) * 16;
    float4 kR[2], vR[2];
    {
        size_t nk0 = (size_t)b * SEQ + kr;
        kR[0] = *(const float4*)&qkv[nk0 * QKVD + DIM + h * HDIM + kd8];
        kR[1] = *(const float4*)&qkv[(nk0 + 32) * QKVD + DIM + h * HDIM + kd8];
        size_t nv0 = (size_t)b * SEQ + vr;
        vR[0] = *(const float4*)&qkv[nv0 * QKVD + 2 * DIM + h * HDIM + vdb];
        vR[1] = *(const float4*)&qkv[nv0 * QKVD + 2 * DIM + h * HDIM + vdb + 8];
    }
    __syncthreads();
    bf16x8 qa0 = *(const bf16x8*)&Qsh[w * 16 + l16][quad * 8];
    bf16x8 qa1 = *(const bf16x8*)&Qsh[w * 16 + l16][32 + quad * 8];

    f32x4 o[4] = {};
    float mrow[4] = {-1e30f, -1e30f, -1e30f, -1e30f};
    float lrow[4] = {};
    const float SCL = 0.125f * 1.44269504f;   // 1/sqrt(64) * log2(e)

#pragma unroll 1
    for (int kt = 0; kt < SEQ / 64; ++kt) {
        *(float4*)&Ksh[kr][kd8]      = kR[0];
        *(float4*)&Ksh[kr + 32][kd8] = kR[1];
        {
            const u16* pa = (const u16*)&vR[0];
            const u16* pb = (const u16*)&vR[1];
#pragma unroll
            for (int j = 0; j < 8; ++j) VshT[vdb + j][vr] = pa[j];
#pragma unroll
            for (int j = 0; j < 8; ++j) VshT[vdb + 8 + j][vr] = pb[j];
        }
        __syncthreads();
        if (kt + 1 < SEQ / 64) {
            size_t nk0 = (size_t)b * SEQ + (kt + 1) * 64 + kr;
            kR[0] = *(const float4*)&qkv[nk0 * QKVD + DIM + h * HDIM + kd8];
            kR[1] = *(const float4*)&qkv[(nk0 + 32) * QKVD + DIM + h * HDIM + kd8];
            size_t nv0 = (size_t)b * SEQ + (kt + 1) * 64 + vr;
            vR[0] = *(const float4*)&qkv[nv0 * QKVD + 2 * DIM + h * HDIM + vdb];
            vR[1] = *(const float4*)&qkv[nv0 * QKVD + 2 * DIM + h * HDIM + vdb + 8];
        }
        float sc[4][4];
#pragma unroll
        for (int c = 0; c < 4; ++c) {
            bf16x8 kb0 = *(const bf16x8*)&Ksh[c * 16 + l16][quad * 8];
            bf16x8 kb1 = *(const bf16x8*)&Ksh[c * 16 + l16][32 + quad * 8];
            f32x4 s = {};
            s = __builtin_amdgcn_mfma_f32_16x16x32_bf16(qa0, kb0, s, 0, 0, 0);
            s = __builtin_amdgcn_mfma_f32_16x16x32_bf16(qa1, kb1, s, 0, 0, 0);
#pragma unroll
            for (int r = 0; r < 4; ++r) sc[c][r] = s[r] * SCL;
        }
        float alpha[4];
#pragma unroll
        for (int r = 0; r < 4; ++r) {
            float mx = fmaxf(fmaxf(sc[0][r], sc[1][r]), fmaxf(sc[2][r], sc[3][r]));
#pragma unroll
            for (int off = 1; off < 16; off <<= 1)
                mx = fmaxf(mx, __shfl_xor(mx, off, 64));
            float mnew = fmaxf(mrow[r], mx);
            alpha[r] = exp2f(mrow[r] - mnew);
            mrow[r] = mnew;
            float sum = 0.f;
#pragma unroll
            for (int c = 0; c < 4; ++c) {
                float p = exp2f(sc[c][r] - mnew);
                sc[c][r] = p;
                sum += p;
            }
#pragma unroll
            for (int off = 1; off < 16; off <<= 1)
                sum += __shfl_xor(sum, off, 64);
            lrow[r] = lrow[r] * alpha[r] + sum;
        }
#pragma unroll
        for (int c = 0; c < 4; ++c)
#pragma unroll
            for (int r = 0; r < 4; ++r)
                Psh[w * 16 + quad * 4 + r][c * 16 + l16] = f2bf(sc[c][r]);
#pragma unroll
        for (int dt = 0; dt < 4; ++dt)
#pragma unroll
            for (int r = 0; r < 4; ++r) o[dt][r] *= alpha[r];
        bf16x8 pa0 = *(const bf16x8*)&Psh[w * 16 + l16][quad * 8];
        bf16x8 pa1 = *(const bf16x8*)&Psh[w * 16 + l16][32 + quad * 8];
#pragma unroll
        for (int dt = 0; dt < 4; ++dt) {
            bf16x8 vb0 = *(const bf16x8*)&VshT[dt * 16 + l16][quad * 8];
            bf16x8 vb1 = *(const bf16x8*)&VshT[dt * 16 + l16][32 + quad * 8];
            o[dt] = __builtin_amdgcn_mfma_f32_16x16x32_bf16(pa0, vb0, o[dt], 0, 0, 0);
            o[dt] = __builtin_amdgcn_mfma_f32_16x16x32_bf16(pa1, vb1, o[dt], 0, 0, 0);
        }
        __syncthreads();
    }
#pragma unroll
    for (int r = 0; r < 4; ++r) {
        float inv = 1.f / lrow[r];
        size_t n = (size_t)b * SEQ + qt * 64 + w * 16 + quad * 4 + r;
#pragma unroll
        for (int dt = 0; dt < 4; ++dt)
            ctx[n * DIM + h * HDIM + dt * 16 + l16] = f2bf(o[dt][r] * inv);
    }
}

// ---------- K3: fused proj+LN1+FF+LN2, 1-wave blocks, zero barriers --------
// Block = 1 wave, 16 rows. All B-fragments from global (L2-hot weights);
// h1/f1 C->A layout bounce via wave-local LDS (no __syncthreads anywhere).
__global__ __launch_bounds__(64)
void projff_kernel(const u16* __restrict__ ctx, const void* __restrict__ oW,
                   const void* __restrict__ oB, const void* __restrict__ W1,
                   const void* __restrict__ b1, const void* __restrict__ W2,
                   const void* __restrict__ b2, const void* __restrict__ g1,
                   const void* __restrict__ e1, const void* __restrict__ g2,
                   const void* __restrict__ e2, const u16* __restrict__ h01,
                   void* __restrict__ outp, const void* __restrict__ x,
                   int arow0, int qrow0) {
    int fbf = detect_fbf((const u16*)x);
    int rs  = fbf ? 128 : 256;
    __shared__ u16 h1sh[16][136];
    __shared__ u16 f1sh[16][136];
    int lane = threadIdx.x;
    int l16 = lane & 15, quad = lane >> 4;
    int n0 = blockIdx.x * 16;

    // ctx A-frags
    bf16x8 af[4];
#pragma unroll
    for (int kk = 0; kk < 4; ++kk)
        af[kk] = *(const bf16x8*)&ctx[(size_t)(qrow0 + n0 + l16) * DIM
                                      + kk * 32 + quad * 8];
    // proj: sa = ctx @ out_w^T
    f32x4 acc[8] = {};
#pragma unroll
    for (int kk = 0; kk < 4; ++kk) {
#pragma unroll
        for (int s = 0; s < 8; ++s) {
            bf16x8 bf = ldbf8(oW, fbf,
                (size_t)(s * 16 + l16) * DIM + kk * 32 + quad * 8);
            acc[s] = __builtin_amdgcn_mfma_f32_16x16x32_bf16(af[kk], bf, acc[s], 0, 0, 0);
        }
    }
    // LN1( sa + oB + h0 ) -> h1sh
#pragma unroll
    for (int r = 0; r < 4; ++r) {
        size_t rg = (size_t)(arow0 + n0 + quad * 4 + r);
        float v[8];
#pragma unroll
        for (int s = 0; s < 8; ++s)
            v[s] = acc[s][r] + ld1(oB, fbf, s * 16 + l16)
                 + bf2f(h01[rg * rs + s * 16 + l16]);
        float sm = 0.f, sq = 0.f;
#pragma unroll
        for (int s = 0; s < 8; ++s) { sm += v[s]; sq += v[s] * v[s]; }
#pragma unroll
        for (int off = 1; off < 16; off <<= 1) {
            sm += __shfl_xor(sm, off, 64);
            sq += __shfl_xor(sq, off, 64);
        }
        float mu  = sm * (1.f / DIM);
        float var = fmaxf(sq * (1.f / DIM) - mu * mu, 0.f);
        float rsq = rsqrtf(var + 1e-5f);
#pragma unroll
        for (int s = 0; s < 8; ++s)
            h1sh[quad * 4 + r][s * 16 + l16] =
                f2bf((v[s] - mu) * rsq * ld1(g1, fbf, s * 16 + l16)
                     + ld1(e1, fbf, s * 16 + l16));
    }
    // h1 A-frags (wave-local LDS round-trip)
    bf16x8 hf[4];
#pragma unroll
    for (int kk = 0; kk < 4; ++kk)
        hf[kk] = *(const bf16x8*)&h1sh[l16][kk * 32 + quad * 8];
    // FF: 4 chunks of 128 ff-cols, all weights from global
    f32x4 acc2[8] = {};
#pragma unroll 1
    for (int c = 0; c < 4; ++c) {
        f32x4 acc1[8] = {};
#pragma unroll
        for (int kk = 0; kk < 4; ++kk) {
#pragma unroll
            for (int s = 0; s < 8; ++s) {
                bf16x8 bf = ldbf8(W1, fbf,
                    (size_t)(c * 128 + s * 16 + l16) * DIM + kk * 32 + quad * 8);
                acc1[s] = __builtin_amdgcn_mfma_f32_16x16x32_bf16(hf[kk], bf, acc1[s], 0, 0, 0);
            }
        }
#pragma unroll
        for (int s = 0; s < 8; ++s) {
            float bb1 = ld1(b1, fbf, c * 128 + s * 16 + l16);
#pragma unroll
            for (int r = 0; r < 4; ++r)
                f1sh[quad * 4 + r][s * 16 + l16] =
                    f2bf(fmaxf(acc1[s][r] + bb1, 0.f));
        }
        bf16x8 pf[4];
#pragma unroll
        for (int kk = 0; kk < 4; ++kk)
            pf[kk] = *(const bf16x8*)&f1sh[l16][kk * 32 + quad * 8];
#pragma unroll
        for (int kk = 0; kk < 4; ++kk) {
#pragma unroll
            for (int s = 0; s < 8; ++s) {
                bf16x8 bf = ldbf8(W2, fbf,
                    (size_t)(s * 16 + l16) * (4 * DIM) + c * 128 + kk * 32 + quad * 8);
                acc2[s] = __builtin_amdgcn_mfma_f32_16x16x32_bf16(pf[kk], bf, acc2[s], 0, 0, 0);
            }
        }
    }
    // LN2( ff + b2 + h1 ) -> final out
#pragma unroll
    for (int r = 0; r < 4; ++r) {
        size_t rg = (size_t)(arow0 + n0 + quad * 4 + r);
        float v[8];
#pragma unroll
        for (int s = 0; s < 8; ++s)
            v[s] = acc2[s][r] + ld1(b2, fbf, s * 16 + l16)
                 + bf2f(h1sh[quad * 4 + r][s * 16 + l16]);
        float sm = 0.f, sq = 0.f;
#pragma unroll
        for (int s = 0; s < 8; ++s) { sm += v[s]; sq += v[s] * v[s]; }
#pragma unroll
        for (int off = 1; off < 16; off <<= 1) {
            sm += __shfl_xor(sm, off, 64);
            sq += __shfl_xor(sq, off, 64);
        }
        float mu  = sm * (1.f / DIM);
        float var = fmaxf(sq * (1.f / DIM) - mu * mu, 0.f);
        float rsq = rsqrtf(var + 1e-5f);
        if (fbf) {
            u16* o = (u16*)outp;
#pragma unroll
            for (int s = 0; s < 8; ++s)
                o[rg * 128 + s * 16 + l16] =
                    f2bf((v[s] - mu) * rsq * ld1(g2, fbf, s * 16 + l16)
                         + ld1(e2, fbf, s * 16 + l16));
        } else {
            float* o = (float*)outp;
#pragma unroll
            for (int s = 0; s < 8; ++s)
                o[rg * 128 + s * 16 + l16] =
                    (v[s] - mu) * rsq * ld1(g2, fbf, s * 16 + l16)
                    + ld1(e2, fbf, s * 16 + l16);
        }
    }
}

// ---------------------------------------------------------------------------
extern "C" void kernel_launch(void* const* d_in, const int* in_sizes, int n_in,
                              void* d_out, int out_size, void* d_ws, size_t ws_size,
                              hipStream_t stream) {
    const void* x     = d_in[0];
    const void* pos   = d_in[1];
    const void* pe_w  = d_in[2];
    const void* pe_b  = d_in[3];
    const void* in_w  = d_in[4];
    const void* in_b  = d_in[5];
    const void* out_w = d_in[6];
    const void* out_b = d_in[7];
    const void* ln1_g = d_in[8];
    const void* ln1_b = d_in[9];
    const void* ln2_g = d_in[10];
    const void* ln2_b = d_in[11];
    const void* ff1_w = d_in[12];
    const void* ff1_b = d_in[13];
    const void* ff2_w = d_in[14];
    const void* ff2_b = d_in[15];

    char* wsb = (char*)d_ws;
    u16*  h01 = (u16*)d_out;    // h0 residual, bf16 in dtype-dependent slots
    const size_t MB = 1024 * 1024;

    if (ws_size >= 17 * MB) {
        // batched: qkv[0,12M), ctx[12M,16M)
        u16* qkv = (u16*)wsb;
        u16* ctx = (u16*)(wsb + 12 * MB);
        peqkv_kernel<<<NTOT / 16, 64, 0, stream>>>(
            x, pos, pe_w, pe_b, in_w, in_b, h01, qkv, 0, 0);
        attn_kernel<<<NGRAPH * NHEAD * 16, 256, 0, stream>>>(qkv, ctx);
        projff_kernel<<<NTOT / 16, 64, 0, stream>>>(
            ctx, out_w, out_b, ff1_w, ff1_b, ff2_w, ff2_b,
            ln1_g, ln1_b, ln2_g, ln2_b, h01, d_out, x, 0, 0);
    } else {
        // per-graph: qkv_g[0,768K), ctx_g[768K,1M)
        u16* qkv_g = (u16*)wsb;
        u16* ctx_g = (u16*)(wsb + 768 * 1024);
        for (int g = 0; g < NGRAPH; ++g) {
            int row0 = g * SEQ;
            peqkv_kernel<<<SEQ / 16, 64, 0, stream>>>(
                x, pos, pe_w, pe_b, in_w, in_b, h01, qkv_g, row0, 0);
            attn_kernel<<<NHEAD * 16, 256, 0, stream>>>(qkv_g, ctx_g);
            projff_kernel<<<SEQ / 16, 64, 0, stream>>>(
                ctx_g, out_w, out_b, ff1_w, ff1_b, ff2_w, ff2_b,
                ln1_g, ln1_b, ln2_g, ln2_b, h01, d_out, x, row0, 0);
        }
    }
}

// Round 11
// 227.431 us; speedup vs baseline: 1.3991x; 1.3991x over previous
//
#include <hip/hip_runtime.h>

typedef unsigned short u16;

#define NGRAPH 16
#define SEQ    1024
#define DIM    128
#define NHEAD  2
#define HDIM   64
#define KPOS   20
#define NTOT   (NGRAPH*SEQ)     // 16384
#define QKVD   (3*DIM)          // 384

// ---------- bf16 helpers ----------------------------------------------------
__device__ __forceinline__ float bf2f(u16 u) {
    return __uint_as_float(((unsigned int)u) << 16);
}
__device__ __forceinline__ u16 f2bf(float f) {
    unsigned int u = __float_as_uint(f);
    u += 0x7fffu + ((u >> 16) & 1u);   // RNE
    return (u16)(u >> 16);
}
__device__ __forceinline__ float ld1(const void* p, int fbf, size_t i) {
    return fbf ? bf2f(((const u16*)p)[i]) : ((const float*)p)[i];
}
// 8 contiguous weights -> packed bf16x8 (as float4 bit pattern)
__device__ __forceinline__ float4 ldw8(const void* W, int fbf, size_t i) {
    if (fbf) return *(const float4*)((const u16*)W + i);
    const float* q = (const float*)W + i;
    float4 a = *(const float4*)q, b = *(const float4*)(q + 4);
    float4 r;
    u16* d = (u16*)&r;
    d[0]=f2bf(a.x); d[1]=f2bf(a.y); d[2]=f2bf(a.z); d[3]=f2bf(a.w);
    d[4]=f2bf(b.x); d[5]=f2bf(b.y); d[6]=f2bf(b.z); d[7]=f2bf(b.w);
    return r;
}

// ---------- K0: dtype detection --------------------------------------------
__global__ void detect_kernel(const u16* __restrict__ x, int* __restrict__ flag) {
    if (threadIdx.x == 0 && blockIdx.x == 0) {
        int ok = 1;
        for (int i = 0; i < 256; i += 2) {
            unsigned e = (x[i] >> 7) & 0xFF;
            if (e < 60u || e > 180u) ok = 0;
        }
        *flag = ok;
    }
}

// ---------- K1: h0 = x + pos_enc @ pe_w.T + pe_b  (bf16, strided slots) ----
__global__ __launch_bounds__(256)
void pe_kernel(const void* __restrict__ x, const void* __restrict__ pos,
               const void* __restrict__ pe_w, const void* __restrict__ pe_b,
               u16* __restrict__ h0, const int* __restrict__ flag) {
    int fbf = *flag;
    __shared__ float wsh[DIM][KPOS + 1];
    int t = threadIdx.x;
    for (int i = t; i < DIM * KPOS; i += 256)
        wsh[i / KPOS][i % KPOS] = ld1(pe_w, fbf, i);
    __syncthreads();
    int row = blockIdx.x * 2 + (t >> 7), d = t & 127;
    float acc = 0.f;
#pragma unroll
    for (int k = 0; k < KPOS; ++k)
        acc += ld1(pos, fbf, (size_t)row * KPOS + k) * wsh[d][k];
    int rs = fbf ? 128 : 256;   // h0 row slot stride (u16 units)
    h0[(size_t)row * rs + d] =
        f2bf(ld1(x, fbf, (size_t)row * DIM + d) + acc + ld1(pe_b, fbf, d));
}

typedef __attribute__((ext_vector_type(8))) short bf16x8;
typedef __attribute__((ext_vector_type(4))) float f32x4;

// ---------- high-occupancy MFMA GEMM: 32-row x 64-col tiles ----------------
// Block 256 = 4 waves; wave w: rows (w&1)*16.., cols (w>>1)*32..
// LDS 26.1 KB -> 6 blocks/CU; grids of 3072-4096 blocks -> ~24 waves/CU.
// EPI 0: +bias -> bf16 out     EPI 1: +bias,relu -> bf16 out
template<int EPI, int NK>
__global__ __launch_bounds__(256)
void mgemm32_kernel(const u16* __restrict__ A, const void* __restrict__ W,
                    const void* __restrict__ bias, u16* __restrict__ out,
                    int Mtot, int AstrIn, int arow0, int orow0,
                    const int* __restrict__ flag) {
    const int K = NK * 128;
    int fbf  = *flag;
    int rs   = fbf ? 128 : 256;
    int Astr = (AstrIn < 0) ? rs : AstrIn;
    __shared__ u16 Ash[32][136];   //  8.7 KB
    __shared__ u16 Wsh[64][136];   // 17.4 KB
    int t = threadIdx.x;
    int w = t >> 6, lane = t & 63, l16 = lane & 15, quad = lane >> 4;
    int wr = (w & 1) * 16, wc = (w >> 1) * 32;
    int n0 = blockIdx.x * 32;
    int m0 = blockIdx.y * 64;
    f32x4 acc[2] = {};
#pragma unroll 1
    for (int c = 0; c < NK; ++c) {
        // stage A 32x128 (2 float4/thread, coalesced)
#pragma unroll
        for (int i = 0; i < 2; ++i) {
            int idx = t + i * 256;
            int row = idx >> 4, k8 = (idx & 15) * 8;
            *(float4*)&Ash[row][k8] =
                *(const float4*)&A[(size_t)(arow0 + n0 + row) * Astr + c * 128 + k8];
        }
        // stage W 64x128 (4 ldw8/thread)
#pragma unroll
        for (int i = 0; i < 4; ++i) {
            int idx = t + i * 256;
            int m = idx >> 4, k8 = (idx & 15) * 8;
            *(float4*)&Wsh[m][k8] = ldw8(W, fbf, (size_t)(m0 + m) * K + c * 128 + k8);
        }
        __syncthreads();
#pragma unroll
        for (int kk = 0; kk < 4; ++kk) {
            bf16x8 af = *(const bf16x8*)&Ash[wr + l16][kk * 32 + quad * 8];
#pragma unroll
            for (int s = 0; s < 2; ++s) {
                bf16x8 bf = *(const bf16x8*)&Wsh[wc + s * 16 + l16][kk * 32 + quad * 8];
                acc[s] = __builtin_amdgcn_mfma_f32_16x16x32_bf16(af, bf, acc[s], 0, 0, 0);
            }
        }
        if (c + 1 < NK) __syncthreads();
    }
    // epilogue
#pragma unroll
    for (int s = 0; s < 2; ++s) {
        int col = m0 + wc + s * 16 + l16;
        float bb = ld1(bias, fbf, col);
#pragma unroll
        for (int r = 0; r < 4; ++r) {
            int lr = wr + quad * 4 + r;
            float v = acc[s][r] + bb;
            if (EPI == 1) v = fmaxf(v, 0.f);
            out[(size_t)(orow0 + n0 + lr) * Mtot + col] = f2bf(v);
        }
    }
}

// ---------- GEMM + bias + resid + LayerNorm: 16-row x 128-col tiles --------
// Block 256 = 4 waves; wave w owns cols w*32..w*32+32 (all 16 rows).
// LDS 39.2 KB -> 4 blocks/CU; grid 1024 -> 16 waves/CU. 2 barriers (NK=1).
// FINAL 0: LN -> bf16 h01 slots.  FINAL 1: LN -> final output (dtype per fbf).
template<int FINAL, int NK>
__global__ __launch_bounds__(256)
void gemmln16_kernel(const u16* __restrict__ A, const void* __restrict__ W,
                     const void* __restrict__ bias, const u16* __restrict__ resid,
                     const void* __restrict__ lng, const void* __restrict__ lnb,
                     void* __restrict__ outp, int Astr, int qrow0, int orow0,
                     const int* __restrict__ flag) {
    const int K = NK * 128;
    int fbf = *flag;
    int rs  = fbf ? 128 : 256;
    __shared__ u16 Wsh[128][136];   // 34.8 KB
    __shared__ u16 Csh[16][136];    //  4.3 KB
    int t = threadIdx.x;
    int w = t >> 6, lane = t & 63, l16 = lane & 15, quad = lane >> 4;
    int n0 = blockIdx.x * 16;
    f32x4 acc[2] = {};
#pragma unroll 1
    for (int c = 0; c < NK; ++c) {
        // stage W 128x128 (8 ldw8/thread)
#pragma unroll
        for (int i = 0; i < 8; ++i) {
            int idx = t + i * 256;
            int m = idx >> 4, k8 = (idx & 15) * 8;
            *(float4*)&Wsh[m][k8] = ldw8(W, fbf, (size_t)m * K + c * 128 + k8);
        }
        __syncthreads();
        // A-frags (all 4 waves load the same 16 rows; L2-hot)
        bf16x8 af[4];
#pragma unroll
        for (int kk = 0; kk < 4; ++kk)
            af[kk] = *(const bf16x8*)&A[(size_t)(qrow0 + n0 + l16) * Astr
                                        + c * 128 + kk * 32 + quad * 8];
#pragma unroll
        for (int kk = 0; kk < 4; ++kk) {
#pragma unroll
            for (int s = 0; s < 2; ++s) {
                bf16x8 bf = *(const bf16x8*)&Wsh[w * 32 + s * 16 + l16][kk * 32 + quad * 8];
                acc[s] = __builtin_amdgcn_mfma_f32_16x16x32_bf16(af[kk], bf, acc[s], 0, 0, 0);
            }
        }
        if (c + 1 < NK) __syncthreads();
    }
    // epilogue: +bias +resid -> Csh (bf16)
#pragma unroll
    for (int s = 0; s < 2; ++s) {
        int col = w * 32 + s * 16 + l16;
        float bb = ld1(bias, fbf, col);
#pragma unroll
        for (int r = 0; r < 4; ++r) {
            int lr = quad * 4 + r;
            size_t rg = (size_t)(orow0 + n0 + lr);
            float v = acc[s][r] + bb + bf2f(resid[rg * rs + col]);
            Csh[lr][col] = f2bf(v);
        }
    }
    __syncthreads();
    // LN: wave w handles rows w*4..w*4+4; lane covers 2 cols
#pragma unroll
    for (int rr = 0; rr < 4; ++rr) {
        int row = w * 4 + rr;
        int c2 = lane * 2;
        float v0 = bf2f(Csh[row][c2]), v1 = bf2f(Csh[row][c2 + 1]);
        float sm = v0 + v1, sq = v0 * v0 + v1 * v1;
#pragma unroll
        for (int off = 32; off > 0; off >>= 1) {
            sm += __shfl_xor(sm, off, 64);
            sq += __shfl_xor(sq, off, 64);
        }
        float mu  = sm * (1.f / DIM);
        float var = fmaxf(sq * (1.f / DIM) - mu * mu, 0.f);
        float rsq = rsqrtf(var + 1e-5f);
        float g0 = ld1(lng, fbf, c2), g1 = ld1(lng, fbf, c2 + 1);
        float b0 = ld1(lnb, fbf, c2), b1 = ld1(lnb, fbf, c2 + 1);
        float o0 = (v0 - mu) * rsq * g0 + b0;
        float o1 = (v1 - mu) * rsq * g1 + b1;
        size_t rg = (size_t)(orow0 + n0 + row);
        if (FINAL) {
            if (fbf) {
                u16* o = (u16*)outp;
                ushort2 u2; u2.x = f2bf(o0); u2.y = f2bf(o1);
                *(ushort2*)&o[rg * 128 + c2] = u2;
            } else {
                float* o = (float*)outp;
                *(float2*)&o[rg * 128 + c2] = make_float2(o0, o1);
            }
        } else {
            u16* o = (u16*)outp;
            ushort2 u2; u2.x = f2bf(o0); u2.y = f2bf(o1);
            *(ushort2*)&o[rg * rs + c2] = u2;
        }
    }
}

// ---------- K3: flash attention (R7 kernel verbatim — measured 47 us) ------
__global__ __launch_bounds__(256)
void attn_kernel(const u16* __restrict__ qkv, u16* __restrict__ ctx) {
    __shared__ u16 Qsh[64][72];
    __shared__ u16 Ksh[64][72];
    __shared__ u16 VshT[64][72];
    __shared__ u16 Psh[64][72];
    int t    = threadIdx.x;
    int w    = t >> 6;
    int lane = t & 63;
    int l16  = lane & 15;
    int quad = lane >> 4;
    int L = blockIdx.x;
    int ngh = gridDim.x >> 4;
    int qt, gh;
    if (ngh >= 8) {           // XCD swizzle: gh%8 == L%8
        int g8 = L & 7; int rest = L >> 3;
        qt = rest & 15; gh = (rest >> 4) * 8 + g8;
    } else {
        qt = L & 15; gh = L >> 4;
    }
    int b = gh >> 1, h = gh & 1;

#pragma unroll
    for (int i = 0; i < 2; ++i) {
        int idx = t + i * 256;
        int r = idx >> 3, d8 = (idx & 7) * 8;
        size_t n = (size_t)b * SEQ + qt * 64 + r;
        *(float4*)&Qsh[r][d8] = *(const float4*)&qkv[n * QKVD + h * HDIM + d8];
    }
    int kr = t >> 3, kd8 = (t & 7) * 8;
    int vr = t & 63, vdb = (t >> 6) * 16;
    float4 kR[2], vR[2];
    {
        size_t nk0 = (size_t)b * SEQ + kr;
        kR[0] = *(const float4*)&qkv[nk0 * QKVD + DIM + h * HDIM + kd8];
        kR[1] = *(const float4*)&qkv[(nk0 + 32) * QKVD + DIM + h * HDIM + kd8];
        size_t nv0 = (size_t)b * SEQ + vr;
        vR[0] = *(const float4*)&qkv[nv0 * QKVD + 2 * DIM + h * HDIM + vdb];
        vR[1] = *(const float4*)&qkv[nv0 * QKVD + 2 * DIM + h * HDIM + vdb + 8];
    }
    __syncthreads();
    bf16x8 qa0 = *(const bf16x8*)&Qsh[w * 16 + l16][quad * 8];
    bf16x8 qa1 = *(const bf16x8*)&Qsh[w * 16 + l16][32 + quad * 8];

    f32x4 o[4] = {};
    float mrow[4] = {-1e30f, -1e30f, -1e30f, -1e30f};
    float lrow[4] = {};
    const float SCL = 0.125f * 1.44269504f;   // 1/sqrt(64) * log2(e)

#pragma unroll 1
    for (int kt = 0; kt < SEQ / 64; ++kt) {
        *(float4*)&Ksh[kr][kd8]      = kR[0];
        *(float4*)&Ksh[kr + 32][kd8] = kR[1];
        {
            const u16* pa = (const u16*)&vR[0];
            const u16* pb = (const u16*)&vR[1];
#pragma unroll
            for (int j = 0; j < 8; ++j) VshT[vdb + j][vr] = pa[j];
#pragma unroll
            for (int j = 0; j < 8; ++j) VshT[vdb + 8 + j][vr] = pb[j];
        }
        __syncthreads();
        if (kt + 1 < SEQ / 64) {
            size_t nk0 = (size_t)b * SEQ + (kt + 1) * 64 + kr;
            kR[0] = *(const float4*)&qkv[nk0 * QKVD + DIM + h * HDIM + kd8];
            kR[1] = *(const float4*)&qkv[(nk0 + 32) * QKVD + DIM + h * HDIM + kd8];
            size_t nv0 = (size_t)b * SEQ + (kt + 1) * 64 + vr;
            vR[0] = *(const float4*)&qkv[nv0 * QKVD + 2 * DIM + h * HDIM + vdb];
            vR[1] = *(const float4*)&qkv[nv0 * QKVD + 2 * DIM + h * HDIM + vdb + 8];
        }
        float sc[4][4];
#pragma unroll
        for (int c = 0; c < 4; ++c) {
            bf16x8 kb0 = *(const bf16x8*)&Ksh[c * 16 + l16][quad * 8];
            bf16x8 kb1 = *(const bf16x8*)&Ksh[c * 16 + l16][32 + quad * 8];
            f32x4 s = {};
            s = __builtin_amdgcn_mfma_f32_16x16x32_bf16(qa0, kb0, s, 0, 0, 0);
            s = __builtin_amdgcn_mfma_f32_16x16x32_bf16(qa1, kb1, s, 0, 0, 0);
#pragma unroll
            for (int r = 0; r < 4; ++r) sc[c][r] = s[r] * SCL;
        }
        float alpha[4];
#pragma unroll
        for (int r = 0; r < 4; ++r) {
            float mx = fmaxf(fmaxf(sc[0][r], sc[1][r]), fmaxf(sc[2][r], sc[3][r]));
#pragma unroll
            for (int off = 1; off < 16; off <<= 1)
                mx = fmaxf(mx, __shfl_xor(mx, off, 64));
            float mnew = fmaxf(mrow[r], mx);
            alpha[r] = exp2f(mrow[r] - mnew);
            mrow[r] = mnew;
            float sum = 0.f;
#pragma unroll
            for (int c = 0; c < 4; ++c) {
                float p = exp2f(sc[c][r] - mnew);
                sc[c][r] = p;
                sum += p;
            }
#pragma unroll
            for (int off = 1; off < 16; off <<= 1)
                sum += __shfl_xor(sum, off, 64);
            lrow[r] = lrow[r] * alpha[r] + sum;
        }
#pragma unroll
        for (int c = 0; c < 4; ++c)
#pragma unroll
            for (int r = 0; r < 4; ++r)
                Psh[w * 16 + quad * 4 + r][c * 16 + l16] = f2bf(sc[c][r]);
#pragma unroll
        for (int dt = 0; dt < 4; ++dt)
#pragma unroll
            for (int r = 0; r < 4; ++r) o[dt][r] *= alpha[r];
        bf16x8 pa0 = *(const bf16x8*)&Psh[w * 16 + l16][quad * 8];
        bf16x8 pa1 = *(const bf16x8*)&Psh[w * 16 + l16][32 + quad * 8];
#pragma unroll
        for (int dt = 0; dt < 4; ++dt) {
            bf16x8 vb0 = *(const bf16x8*)&VshT[dt * 16 + l16][quad * 8];
            bf16x8 vb1 = *(const bf16x8*)&VshT[dt * 16 + l16][32 + quad * 8];
            o[dt] = __builtin_amdgcn_mfma_f32_16x16x32_bf16(pa0, vb0, o[dt], 0, 0, 0);
            o[dt] = __builtin_amdgcn_mfma_f32_16x16x32_bf16(pa1, vb1, o[dt], 0, 0, 0);
        }
        __syncthreads();
    }
#pragma unroll
    for (int r = 0; r < 4; ++r) {
        float inv = 1.f / lrow[r];
        size_t n = (size_t)b * SEQ + qt * 64 + w * 16 + quad * 4 + r;
#pragma unroll
        for (int dt = 0; dt < 4; ++dt)
            ctx[n * DIM + h * HDIM + dt * 16 + l16] = f2bf(o[dt][r] * inv);
    }
}

// ---------------------------------------------------------------------------
extern "C" void kernel_launch(void* const* d_in, const int* in_sizes, int n_in,
                              void* d_out, int out_size, void* d_ws, size_t ws_size,
                              hipStream_t stream) {
    const void* x     = d_in[0];
    const void* pos   = d_in[1];
    const void* pe_w  = d_in[2];
    const void* pe_b  = d_in[3];
    const void* in_w  = d_in[4];
    const void* in_b  = d_in[5];
    const void* out_w = d_in[6];
    const void* out_b = d_in[7];
    const void* ln1_g = d_in[8];
    const void* ln1_b = d_in[9];
    const void* ln2_g = d_in[10];
    const void* ln2_b = d_in[11];
    const void* ff1_w = d_in[12];
    const void* ff1_b = d_in[13];
    const void* ff2_w = d_in[14];
    const void* ff2_b = d_in[15];

    char* wsb  = (char*)d_ws;
    int*  flag = (int*)(wsb + ((ws_size - 4) & ~(size_t)3));
    u16*  h01  = (u16*)d_out;   // h0 then h1, bf16 in dtype-dependent row slots
    const size_t MB = 1024 * 1024;

    detect_kernel<<<1, 1, 0, stream>>>((const u16*)x, flag);
    pe_kernel<<<NTOT / 2, 256, 0, stream>>>(x, pos, pe_w, pe_b, h01, flag);

    if (ws_size >= 17 * MB) {
        // batched: qkv[0,12M), ctx[12M,16M), f1 reuses [0,16.8M)
        u16* qkv = (u16*)wsb;
        u16* ctx = (u16*)(wsb + 12 * MB);
        u16* f1  = (u16*)wsb;
        mgemm32_kernel<0,1><<<dim3(NTOT / 32, 6), 256, 0, stream>>>(
            h01, in_w, in_b, qkv, QKVD, -1, 0, 0, flag);
        attn_kernel<<<NGRAPH * NHEAD * 16, 256, 0, stream>>>(qkv, ctx);
        gemmln16_kernel<0,1><<<NTOT / 16, 256, 0, stream>>>(
            ctx, out_w, out_b, h01, ln1_g, ln1_b, h01, DIM, 0, 0, flag);
        mgemm32_kernel<1,1><<<dim3(NTOT / 32, 8), 256, 0, stream>>>(
            h01, ff1_w, ff1_b, f1, 4 * DIM, -1, 0, 0, flag);
        gemmln16_kernel<1,4><<<NTOT / 16, 256, 0, stream>>>(
            f1, ff2_w, ff2_b, h01, ln2_g, ln2_b, d_out, 4 * DIM, 0, 0, flag);
    } else {
        // per-graph: qkv_g[0,768K), ctx_g[768K,1M), f1_g reuses [0,1M)
        u16* qkv_g = (u16*)wsb;
        u16* ctx_g = (u16*)(wsb + 768 * 1024);
        u16* f1_g  = (u16*)wsb;
        for (int g = 0; g < NGRAPH; ++g) {
            int row0 = g * SEQ;
            mgemm32_kernel<0,1><<<dim3(SEQ / 32, 6), 256, 0, stream>>>(
                h01, in_w, in_b, qkv_g, QKVD, -1, row0, 0, flag);
            attn_kernel<<<NHEAD * 16, 256, 0, stream>>>(qkv_g, ctx_g);
            gemmln16_kernel<0,1><<<SEQ / 16, 256, 0, stream>>>(
                ctx_g, out_w, out_b, h01, ln1_g, ln1_b, h01, DIM, 0, row0, flag);
        }
        for (int g = 0; g < NGRAPH; ++g) {
            int row0 = g * SEQ;
            mgemm32_kernel<1,1><<<dim3(SEQ / 32, 8), 256, 0, stream>>>(
                h01, ff1_w, ff1_b, f1_g, 4 * DIM, -1, row0, 0, flag);
            gemmln16_kernel<1,4><<<SEQ / 16, 256, 0, stream>>>(
                f1_g, ff2_w, ff2_b, h01, ln2_g, ln2_b, d_out, 4 * DIM, 0, row0, flag);
        }
    }
}